// Round 5
// baseline (3551.721 us; speedup 1.0000x reference)
//
#include <hip/hip_runtime.h>
#include <hip/hip_bf16.h>

#define TM 64
#define TN 64
#define KB 16

__device__ __forceinline__ float sigmoidf_(float x) { return 1.0f / (1.0f + expf(-x)); }

// ---------------- Encoder leaf (d=6): children zero, gh = ebh ----------------
__global__ __launch_bounds__(256) void enc_leaf(
    const float* __restrict__ ewi, const float* __restrict__ ebi,
    const float* __restrict__ ebh, const int* __restrict__ symbols,
    float* __restrict__ hout)
{
    int idx = blockIdx.x * 256 + threadIdx.x;   // over 16384*512
    int c = idx & 511;
    int m = idx >> 9;
    int b = m >> 6, j = m & 63;
    int sym = symbols[b * 127 + 63 + j];
    float r = sigmoidf_(ewi[c * 32 + sym]          + ebi[c]        + ebh[c]);
    float z = sigmoidf_(ewi[(512 + c) * 32 + sym]  + ebi[512 + c]  + ebh[512 + c]);
    float n = tanhf(    ewi[(1024 + c) * 32 + sym] + ebi[1024 + c] + r * ebh[1024 + c]);
    hout[idx] = (1.0f - z) * n;
}

// ---------------- Encoder GEMM + GRU (levels d=5..0) ----------------
// A: (M,1024) f32 (row m = [h_prev[2m], h_prev[2m+1]] contiguous); ewh: (1536,1024);
// hout: (M,512). grid = (M/64, 8), block = 256 (16x16 threads, 4x4 micro, 3 gates).
__global__ __launch_bounds__(256) void enc_gemm(
    const float* __restrict__ A, const float* __restrict__ ewh,
    const float* __restrict__ ewi, const float* __restrict__ ebi,
    const float* __restrict__ ebh, const int* __restrict__ symbols,
    float* __restrict__ hout, int dlog, int node_base)
{
    __shared__ float As[TM][KB + 1];
    __shared__ float Bs[3][TN][KB + 1];
    int tid = threadIdx.x;
    int tx = tid & 15, ty = tid >> 4;
    int m0 = blockIdx.x * TM;
    int c0 = blockIdx.y * TN;
    float acc[3][4][4] = {};

    for (int k0 = 0; k0 < 1024; k0 += KB) {
        int r = tid >> 2;
        int kk = (tid & 3) * 4;
        {
            float4 v = *reinterpret_cast<const float4*>(&A[(size_t)(m0 + r) * 1024 + k0 + kk]);
            As[r][kk] = v.x; As[r][kk + 1] = v.y; As[r][kk + 2] = v.z; As[r][kk + 3] = v.w;
        }
#pragma unroll
        for (int s = 0; s < 3; ++s) {
            float4 v = *reinterpret_cast<const float4*>(&ewh[(size_t)(s * 512 + c0 + r) * 1024 + k0 + kk]);
            Bs[s][r][kk] = v.x; Bs[s][r][kk + 1] = v.y; Bs[s][r][kk + 2] = v.z; Bs[s][r][kk + 3] = v.w;
        }
        __syncthreads();
#pragma unroll
        for (int k = 0; k < KB; ++k) {
            float a[4], bb[3][4];
#pragma unroll
            for (int i = 0; i < 4; ++i) a[i] = As[ty * 4 + i][k];
#pragma unroll
            for (int s = 0; s < 3; ++s)
#pragma unroll
                for (int j = 0; j < 4; ++j) bb[s][j] = Bs[s][tx * 4 + j][k];
#pragma unroll
            for (int s = 0; s < 3; ++s)
#pragma unroll
                for (int i = 0; i < 4; ++i)
#pragma unroll
                    for (int j = 0; j < 4; ++j) acc[s][i][j] += a[i] * bb[s][j];
        }
        __syncthreads();
    }

    int mask = (1 << dlog) - 1;
#pragma unroll
    for (int i = 0; i < 4; ++i) {
        int m = m0 + ty * 4 + i;
        int b = m >> dlog;
        int j = m & mask;
        int sym = symbols[b * 127 + node_base + j];
#pragma unroll
        for (int jj = 0; jj < 4; ++jj) {
            int c = c0 + tx * 4 + jj;
            float r = sigmoidf_(ewi[c * 32 + sym]          + ebi[c]        + acc[0][i][jj] + ebh[c]);
            float z = sigmoidf_(ewi[(512 + c) * 32 + sym]  + ebi[512 + c]  + acc[1][i][jj] + ebh[512 + c]);
            float n = tanhf(    ewi[(1024 + c) * 32 + sym] + ebi[1024 + c] + r * (acc[2][i][jj] + ebh[1024 + c]));
            float hl = A[(size_t)m * 1024 + c];
            float hr = A[(size_t)m * 1024 + 512 + c];
            hout[(size_t)m * 512 + c] = (1.0f - z) * n + z * (hl + hr) * 0.5f;
        }
    }
}

// ---------------- mid: mu/logvar/zlat ----------------
__global__ __launch_bounds__(256) void mid1(
    const float* __restrict__ root, const float* __restrict__ h2mu_w,
    const float* __restrict__ h2mu_b, const float* __restrict__ h2lv_w,
    const float* __restrict__ h2lv_b, const float* __restrict__ eps,
    float* __restrict__ zlat, float* __restrict__ out_mu,
    float* __restrict__ out_lv)
{
    int b = blockIdx.x, t = threadIdx.x;
    __shared__ float rs[512];
    rs[t]       = root[(size_t)b * 512 + t];
    rs[t + 256] = root[(size_t)b * 512 + t + 256];
    __syncthreads();
    const float* w = (t < 128) ? (h2mu_w + (size_t)t * 512) : (h2lv_w + (size_t)(t - 128) * 512);
    float acc = 0.0f;
    for (int k = 0; k < 512; ++k) acc += rs[k] * w[k];
    acc += (t < 128) ? h2mu_b[t] : h2lv_b[t - 128];
    __shared__ float vals[256];
    vals[t] = acc;
    __syncthreads();
    if (t < 128) {
        float mu = vals[t], lv = vals[t + 128];
        float zl = mu + eps[b * 128 + t] * expf(0.5f * lv);
        zlat[b * 128 + t] = zl;
        out_mu[b * 128 + t] = mu;
        out_lv[b * 128 + t] = lv;
    }
}

// hidden0 = zlat @ z2h_w.T + z2h_b : (256,512)
__global__ __launch_bounds__(512) void mid2(
    const float* __restrict__ zlat, const float* __restrict__ z2h_w,
    const float* __restrict__ z2h_b, float* __restrict__ hidden)
{
    int b = blockIdx.x, t = threadIdx.x;
    __shared__ float zs[128];
    if (t < 128) zs[t] = zlat[b * 128 + t];
    __syncthreads();
    float acc = z2h_b[t];
    for (int k = 0; k < 128; ++k) acc += zs[k] * z2h_w[(size_t)t * 128 + k];
    hidden[(size_t)b * 512 + t] = acc;
}

// ---------------- decoder: pred + softmax (block = 8 rows x 32 lanes) ----------------
__global__ __launch_bounds__(256) void dec_pred(
    const float* __restrict__ hidden, const float* __restrict__ h2o_w,
    const float* __restrict__ h2o_b, float* __restrict__ aout,
    float* __restrict__ preds_out, int dlog, int node_base, int write_a)
{
    int tid = threadIdx.x;
    int s = tid & 31, r = tid >> 5;
    __shared__ float hs[8][512];
    {
        const float4* src4 = reinterpret_cast<const float4*>(hidden + (size_t)blockIdx.x * 8 * 512);
        float4* h4 = reinterpret_cast<float4*>(&hs[0][0]);
#pragma unroll
        for (int it = 0; it < 4; ++it) h4[it * 256 + tid] = src4[it * 256 + tid];
    }
    __syncthreads();
    const float4* wrow = reinterpret_cast<const float4*>(h2o_w + (size_t)s * 512);
    const float4* hrow = reinterpret_cast<const float4*>(&hs[r][0]);
    float acc = 0.0f;
#pragma unroll 8
    for (int k = 0; k < 128; ++k) {
        float4 w = wrow[k], h = hrow[k];
        acc += w.x * h.x + w.y * h.y + w.z * h.z + w.w * h.w;
    }
    acc += h2o_b[s];
    float mx = acc;
#pragma unroll
    for (int off = 16; off; off >>= 1) mx = fmaxf(mx, __shfl_xor(mx, off, 32));
    float e = expf(acc - mx);
    float sum = e;
#pragma unroll
    for (int off = 16; off; off >>= 1) sum += __shfl_xor(sum, off, 32);
    float a = e / sum;

    int m = blockIdx.x * 8 + r;
    int b = m >> dlog;
    int j = m & ((1 << dlog) - 1);
    preds_out[(size_t)(b * 127 + node_base + j) * 32 + s] = acc;
    if (write_a) aout[(size_t)m * 32 + s] = a;
}

// ---------------- decoder GRU (levels d=0..5) ----------------
// Hin: (M,512); aBuf: (M,32); Hout: (M,1024) = (2M,512) children. grid = (M/64, 16).
__global__ __launch_bounds__(256) void dec_gru(
    const float* __restrict__ Hin, const float* __restrict__ aBuf,
    const float* __restrict__ dwh, const float* __restrict__ dwi,
    const float* __restrict__ dbh, const float* __restrict__ dbi,
    float* __restrict__ Hout)
{
    __shared__ float As[TM][KB + 1];
    __shared__ float Bs[3][TN][KB + 1];
    int tid = threadIdx.x;
    int tx = tid & 15, ty = tid >> 4;
    int m0 = blockIdx.x * TM;
    int c0 = blockIdx.y * TN;   // column tile within 1024
    float acc[4][4][4] = {};

    for (int k0 = 0; k0 < 544; k0 += KB) {
        int r = tid >> 2;
        int kk = (tid & 3) * 4;
        if (k0 < 512) {
            float4 v = *reinterpret_cast<const float4*>(&Hin[(size_t)(m0 + r) * 512 + k0 + kk]);
            As[r][kk] = v.x; As[r][kk + 1] = v.y; As[r][kk + 2] = v.z; As[r][kk + 3] = v.w;
#pragma unroll
            for (int s = 0; s < 3; ++s) {
                float4 w = *reinterpret_cast<const float4*>(&dwh[(size_t)(s * 1024 + c0 + r) * 512 + k0 + kk]);
                Bs[s][r][kk] = w.x; Bs[s][r][kk + 1] = w.y; Bs[s][r][kk + 2] = w.z; Bs[s][r][kk + 3] = w.w;
            }
        } else {
            int k2 = k0 - 512;
            float4 v = *reinterpret_cast<const float4*>(&aBuf[(size_t)(m0 + r) * 32 + k2 + kk]);
            As[r][kk] = v.x; As[r][kk + 1] = v.y; As[r][kk + 2] = v.z; As[r][kk + 3] = v.w;
#pragma unroll
            for (int s = 0; s < 3; ++s) {
                float4 w = *reinterpret_cast<const float4*>(&dwi[(size_t)(s * 1024 + c0 + r) * 32 + k2 + kk]);
                Bs[s][r][kk] = w.x; Bs[s][r][kk + 1] = w.y; Bs[s][r][kk + 2] = w.z; Bs[s][r][kk + 3] = w.w;
            }
        }
        __syncthreads();
        if (k0 < 512) {
#pragma unroll
            for (int k = 0; k < KB; ++k) {
                float a[4], bb[3][4];
#pragma unroll
                for (int i = 0; i < 4; ++i) a[i] = As[ty * 4 + i][k];
#pragma unroll
                for (int s = 0; s < 3; ++s)
#pragma unroll
                    for (int j = 0; j < 4; ++j) bb[s][j] = Bs[s][tx * 4 + j][k];
#pragma unroll
                for (int i = 0; i < 4; ++i)
#pragma unroll
                    for (int j = 0; j < 4; ++j) {
                        acc[0][i][j] += a[i] * bb[0][j];
                        acc[1][i][j] += a[i] * bb[1][j];
                        acc[2][i][j] += a[i] * bb[2][j];
                    }
            }
        } else {
#pragma unroll
            for (int k = 0; k < KB; ++k) {
                float a[4], bb[3][4];
#pragma unroll
                for (int i = 0; i < 4; ++i) a[i] = As[ty * 4 + i][k];
#pragma unroll
                for (int s = 0; s < 3; ++s)
#pragma unroll
                    for (int j = 0; j < 4; ++j) bb[s][j] = Bs[s][tx * 4 + j][k];
#pragma unroll
                for (int i = 0; i < 4; ++i)
#pragma unroll
                    for (int j = 0; j < 4; ++j) {
                        acc[0][i][j] += a[i] * bb[0][j];
                        acc[1][i][j] += a[i] * bb[1][j];
                        acc[3][i][j] += a[i] * bb[2][j];
                    }
            }
        }
        __syncthreads();
    }

#pragma unroll
    for (int i = 0; i < 4; ++i) {
        int m = m0 + ty * 4 + i;
#pragma unroll
        for (int jj = 0; jj < 4; ++jj) {
            int c = c0 + tx * 4 + jj;
            float r = sigmoidf_(acc[0][i][jj] + dbh[c] + dbi[c]);
            float z = sigmoidf_(acc[1][i][jj] + dbh[1024 + c] + dbi[1024 + c]);
            float n = tanhf(acc[3][i][jj] + dbi[2048 + c] + r * (acc[2][i][jj] + dbh[2048 + c]));
            float hid = Hin[(size_t)m * 512 + (c & 511)];
            Hout[(size_t)m * 1024 + c] = (1.0f - z) * n + z * hid;
        }
    }
}

extern "C" void kernel_launch(void* const* d_in, const int* in_sizes, int n_in,
                              void* d_out, int out_size, void* d_ws, size_t ws_size,
                              hipStream_t stream) {
    const int*   symbols = (const int*)  d_in[0];
    const float* eps     = (const float*)d_in[1];
    const float* ewi     = (const float*)d_in[2];
    const float* ebi     = (const float*)d_in[3];
    const float* ewh     = (const float*)d_in[4];
    const float* ebh     = (const float*)d_in[5];
    const float* h2mu_w  = (const float*)d_in[6];
    const float* h2mu_b  = (const float*)d_in[7];
    const float* h2lv_w  = (const float*)d_in[8];
    const float* h2lv_b  = (const float*)d_in[9];
    const float* z2h_w   = (const float*)d_in[10];
    const float* z2h_b   = (const float*)d_in[11];
    const float* h2o_w   = (const float*)d_in[12];
    const float* h2o_b   = (const float*)d_in[13];
    const float* dwi     = (const float*)d_in[14];
    const float* dbi     = (const float*)d_in[15];
    const float* dwh     = (const float*)d_in[16];
    const float* dbh     = (const float*)d_in[17];

    // ---- f32 outputs: [mu (256x128) | logvar (256x128) | preds (256x127x32)] ----
    float* out    = (float*)d_out;
    float* out_mu = out;
    float* out_lv = out + 256 * 128;
    float* out_pr = out + 2 * 256 * 128;

    // ---- workspace: f32 (51.5 MB) ----
    float* bufL = (float*)d_ws;                          // 16384*512 f32 = 33.55 MB
    float* bufS = bufL + (size_t)16384 * 512;            //  8192*512 f32 = 16.78 MB
    float* zlat = bufS + (size_t)8192 * 512;             //  256*128 f32
    float* aBuf = zlat + 256 * 128;                      //  8192*32 f32

    // ---- encoder ----
    enc_leaf<<<32768, 256, 0, stream>>>(ewi, ebi, ebh, symbols, bufL);
    const float* src = bufL;
    float*       dst = bufS;
    for (int d = 5; d >= 0; --d) {
        int M = 256 << d;
        enc_gemm<<<dim3(M / TM, 8), 256, 0, stream>>>(src, ewh, ewi, ebi, ebh, symbols,
                                                      dst, d, (1 << d) - 1);
        const float* t = src; src = dst; dst = (float*)t;
    }
    // root in bufL (src == bufL after 6 swaps)
    mid1<<<256, 256, 0, stream>>>(src, h2mu_w, h2mu_b, h2lv_w, h2lv_b, eps, zlat, out_mu, out_lv);
    mid2<<<256, 512, 0, stream>>>(zlat, z2h_w, z2h_b, bufL);   // hidden0 -> bufL (root consumed)

    // ---- decoder ----  parity: d even writes bufS, d odd writes bufL; d=5 -> bufL (16384 rows OK)
    const float* hsrc = bufL;
    float*       hdst = bufS;
    for (int d = 0; d < 6; ++d) {
        int M = 256 << d;
        dec_pred<<<M / 8, 256, 0, stream>>>(hsrc, h2o_w, h2o_b, aBuf, out_pr, d, (1 << d) - 1, 1);
        dec_gru<<<dim3(M / TM, 16), 256, 0, stream>>>(hsrc, aBuf, dwh, dwi, dbh, dbi, hdst);
        const float* t = hsrc; hsrc = hdst; hdst = (float*)t;
    }
    dec_pred<<<16384 / 8, 256, 0, stream>>>(hsrc, h2o_w, h2o_b, aBuf, out_pr, 6, 63, 0);
}

// Round 6
// 1630.810 us; speedup vs baseline: 2.1779x; 2.1779x over previous
//
#include <hip/hip_runtime.h>
#include <hip/hip_bf16.h>

typedef unsigned short u16;
typedef unsigned int u32;
typedef __attribute__((ext_vector_type(8))) short short8;   // 8 bf16 = 4 VGPR
typedef __attribute__((ext_vector_type(4))) float f32x4;

__device__ __forceinline__ float sigmoidf_(float x) { return 1.0f / (1.0f + expf(-x)); }

__device__ __forceinline__ float bf2f(u16 u) {
    union { u32 i; float f; } v; v.i = ((u32)u) << 16; return v.f;
}
__device__ __forceinline__ u16 f2bf(float f) {
    union { float f; u32 i; } v; v.f = f;
    u32 lsb = (v.i >> 16) & 1u;
    v.i += 0x7fffu + lsb;            // RNE
    return (u16)(v.i >> 16);
}

// ---------------- f32 -> bf16 weight conversion ----------------
__global__ __launch_bounds__(256) void cvt_bf16(const float* __restrict__ src,
                                                u16* __restrict__ dst, int n)
{
    int i = blockIdx.x * 256 + threadIdx.x;
    if (i < n) dst[i] = f2bf(src[i]);
}

// ---------------- Encoder leaf (d=6) ----------------
__global__ __launch_bounds__(256) void enc_leaf(
    const float* __restrict__ ewi, const float* __restrict__ ebi,
    const float* __restrict__ ebh, const int* __restrict__ symbols,
    u16* __restrict__ hout)
{
    int idx = blockIdx.x * 256 + threadIdx.x;   // over 16384*512
    int c = idx & 511;
    int m = idx >> 9;
    int b = m >> 6, j = m & 63;
    int sym = symbols[b * 127 + 63 + j];
    float r = sigmoidf_(ewi[c * 32 + sym]          + ebi[c]        + ebh[c]);
    float z = sigmoidf_(ewi[(512 + c) * 32 + sym]  + ebi[512 + c]  + ebh[512 + c]);
    float n = tanhf(    ewi[(1024 + c) * 32 + sym] + ebi[1024 + c] + r * ebh[1024 + c]);
    hout[idx] = f2bf((1.0f - z) * n);
}

// ---------------- Encoder MFMA GEMM + GRU (levels d=5..0) ----------------
// A: (M,1024) bf16; W: ewh bf16 (1536,1024); hout: (M,512) bf16.
// grid=(M/64, 8), block=256 (4 waves; wave w: rows m0+16w..+15; 64 cols x 3 gates).
__global__ __launch_bounds__(256) void enc_mfma(
    const u16* __restrict__ A, const u16* __restrict__ W,
    const float* __restrict__ ewi, const float* __restrict__ ebi,
    const float* __restrict__ ebh, const int* __restrict__ symbols,
    u16* __restrict__ hout, int dlog, int node_base)
{
    int wid  = threadIdx.x >> 6;
    int lane = threadIdx.x & 63;
    int lr = lane & 15;          // A-row / B-col / D-col
    int lk = lane >> 4;          // k sub-block
    int m0 = blockIdx.x * 64 + wid * 16;
    int c0 = blockIdx.y * 64;

    f32x4 acc[3][4];
#pragma unroll
    for (int s = 0; s < 3; ++s)
#pragma unroll
        for (int t = 0; t < 4; ++t) acc[s][t] = (f32x4){0.f, 0.f, 0.f, 0.f};

    const u16* Arow = A + (size_t)(m0 + lr) * 1024 + lk * 8;
    const u16* Brow[3][4];
#pragma unroll
    for (int s = 0; s < 3; ++s)
#pragma unroll
        for (int t = 0; t < 4; ++t)
            Brow[s][t] = W + (size_t)(s * 512 + c0 + t * 16 + lr) * 1024 + lk * 8;

    for (int k0 = 0; k0 < 1024; k0 += 32) {
        short8 af = *reinterpret_cast<const short8*>(Arow + k0);
#pragma unroll
        for (int s = 0; s < 3; ++s)
#pragma unroll
            for (int t = 0; t < 4; ++t) {
                short8 bf = *reinterpret_cast<const short8*>(Brow[s][t] + k0);
                acc[s][t] = __builtin_amdgcn_mfma_f32_16x16x32_bf16(af, bf, acc[s][t], 0, 0, 0);
            }
    }

    int mask = (1 << dlog) - 1;
#pragma unroll
    for (int r = 0; r < 4; ++r) {
        int m = m0 + lk * 4 + r;
        int b = m >> dlog, j = m & mask;
        int sym = symbols[b * 127 + node_base + j];
#pragma unroll
        for (int t = 0; t < 4; ++t) {
            int c = c0 + t * 16 + lr;
            float rr = sigmoidf_(ewi[c * 32 + sym]          + ebi[c]        + acc[0][t][r] + ebh[c]);
            float zz = sigmoidf_(ewi[(512 + c) * 32 + sym]  + ebi[512 + c]  + acc[1][t][r] + ebh[512 + c]);
            float nn = tanhf(    ewi[(1024 + c) * 32 + sym] + ebi[1024 + c] + rr * (acc[2][t][r] + ebh[1024 + c]));
            float hl = bf2f(A[(size_t)m * 1024 + c]);
            float hr = bf2f(A[(size_t)m * 1024 + 512 + c]);
            hout[(size_t)m * 512 + c] = f2bf((1.0f - zz) * nn + zz * (hl + hr) * 0.5f);
        }
    }
}

// ---------------- mid: mu/logvar/zlat ----------------
__global__ __launch_bounds__(256) void mid1(
    const u16* __restrict__ root, const float* __restrict__ h2mu_w,
    const float* __restrict__ h2mu_b, const float* __restrict__ h2lv_w,
    const float* __restrict__ h2lv_b, const float* __restrict__ eps,
    float* __restrict__ zlat, float* __restrict__ out_mu,
    float* __restrict__ out_lv)
{
    int b = blockIdx.x, t = threadIdx.x;
    __shared__ float rs[512];
    rs[t]       = bf2f(root[(size_t)b * 512 + t]);
    rs[t + 256] = bf2f(root[(size_t)b * 512 + t + 256]);
    __syncthreads();
    const float* w = (t < 128) ? (h2mu_w + (size_t)t * 512) : (h2lv_w + (size_t)(t - 128) * 512);
    float acc = 0.0f;
    for (int k = 0; k < 512; ++k) acc += rs[k] * w[k];
    acc += (t < 128) ? h2mu_b[t] : h2lv_b[t - 128];
    __shared__ float vals[256];
    vals[t] = acc;
    __syncthreads();
    if (t < 128) {
        float mu = vals[t], lv = vals[t + 128];
        float zl = mu + eps[b * 128 + t] * expf(0.5f * lv);
        zlat[b * 128 + t] = zl;
        out_mu[b * 128 + t] = mu;
        out_lv[b * 128 + t] = lv;
    }
}

__global__ __launch_bounds__(512) void mid2(
    const float* __restrict__ zlat, const float* __restrict__ z2h_w,
    const float* __restrict__ z2h_b, u16* __restrict__ hidden)
{
    int b = blockIdx.x, t = threadIdx.x;
    __shared__ float zs[128];
    if (t < 128) zs[t] = zlat[b * 128 + t];
    __syncthreads();
    float acc = z2h_b[t];
    for (int k = 0; k < 128; ++k) acc += zs[k] * z2h_w[(size_t)t * 128 + k];
    hidden[(size_t)b * 512 + t] = f2bf(acc);
}

// ---------------- decoder: pred + softmax (8 rows x 32 lanes) ----------------
__global__ __launch_bounds__(256) void dec_pred(
    const u16* __restrict__ hidden, const float* __restrict__ h2o_w,
    const float* __restrict__ h2o_b, u16* __restrict__ aout,
    float* __restrict__ preds_out, int dlog, int node_base, int write_a)
{
    int tid = threadIdx.x;
    int s = tid & 31, r = tid >> 5;
    __shared__ float hs[8][512];
    {
        const uint4* src4 = reinterpret_cast<const uint4*>(hidden + (size_t)blockIdx.x * 4096);
#pragma unroll
        for (int it = 0; it < 2; ++it) {
            int q = it * 256 + tid;            // [0,512)
            uint4 u = src4[q];
            int base = q * 8;
            int rr = base >> 9, cc = base & 511;
            hs[rr][cc + 0] = bf2f((u16)(u.x & 0xffff)); hs[rr][cc + 1] = bf2f((u16)(u.x >> 16));
            hs[rr][cc + 2] = bf2f((u16)(u.y & 0xffff)); hs[rr][cc + 3] = bf2f((u16)(u.y >> 16));
            hs[rr][cc + 4] = bf2f((u16)(u.z & 0xffff)); hs[rr][cc + 5] = bf2f((u16)(u.z >> 16));
            hs[rr][cc + 6] = bf2f((u16)(u.w & 0xffff)); hs[rr][cc + 7] = bf2f((u16)(u.w >> 16));
        }
    }
    __syncthreads();
    const float4* wrow = reinterpret_cast<const float4*>(h2o_w + (size_t)s * 512);
    const float4* hrow = reinterpret_cast<const float4*>(&hs[r][0]);
    float acc = 0.0f;
#pragma unroll 8
    for (int k = 0; k < 128; ++k) {
        float4 w = wrow[k], h = hrow[k];
        acc += w.x * h.x + w.y * h.y + w.z * h.z + w.w * h.w;
    }
    acc += h2o_b[s];
    float mx = acc;
#pragma unroll
    for (int off = 16; off; off >>= 1) mx = fmaxf(mx, __shfl_xor(mx, off, 32));
    float e = expf(acc - mx);
    float sum = e;
#pragma unroll
    for (int off = 16; off; off >>= 1) sum += __shfl_xor(sum, off, 32);
    float a = e / sum;

    int m = blockIdx.x * 8 + r;
    int b = m >> dlog;
    int j = m & ((1 << dlog) - 1);
    preds_out[(size_t)(b * 127 + node_base + j) * 32 + s] = acc;
    if (write_a) aout[(size_t)m * 32 + s] = f2bf(a);
}

// ---------------- decoder MFMA GRU (levels d=0..5) ----------------
// Hin: (M,512) bf16; aB: (M,32) bf16; Wh: dwh bf16 (3072,512); Wi: dwi bf16 (3072,32);
// Hout: (M,1024) bf16. grid=(M/64, 16), block=256.
// acc[0]=r (Wh+Wi), acc[1]=z (Wh+Wi), acc[2]=gh_n (Wh), acc[3]=gi_n (Wi)
__global__ __launch_bounds__(256) void dec_mfma(
    const u16* __restrict__ Hin, const u16* __restrict__ aB,
    const u16* __restrict__ Wh, const u16* __restrict__ Wi,
    const float* __restrict__ dbh, const float* __restrict__ dbi,
    u16* __restrict__ Hout)
{
    int wid  = threadIdx.x >> 6;
    int lane = threadIdx.x & 63;
    int lr = lane & 15;
    int lk = lane >> 4;
    int m0 = blockIdx.x * 64 + wid * 16;
    int c0 = blockIdx.y * 64;     // within 1024

    f32x4 acc[4][4];
#pragma unroll
    for (int s = 0; s < 4; ++s)
#pragma unroll
        for (int t = 0; t < 4; ++t) acc[s][t] = (f32x4){0.f, 0.f, 0.f, 0.f};

    const u16* Arow = Hin + (size_t)(m0 + lr) * 512 + lk * 8;
    const u16* Brow[3][4];
#pragma unroll
    for (int s = 0; s < 3; ++s)
#pragma unroll
        for (int t = 0; t < 4; ++t)
            Brow[s][t] = Wh + (size_t)(s * 1024 + c0 + t * 16 + lr) * 512 + lk * 8;

    for (int k0 = 0; k0 < 512; k0 += 32) {
        short8 af = *reinterpret_cast<const short8*>(Arow + k0);
#pragma unroll
        for (int s = 0; s < 3; ++s)
#pragma unroll
            for (int t = 0; t < 4; ++t) {
                short8 bf = *reinterpret_cast<const short8*>(Brow[s][t] + k0);
                acc[s][t] = __builtin_amdgcn_mfma_f32_16x16x32_bf16(af, bf, acc[s][t], 0, 0, 0);
            }
    }
    // input-gate contribution, K=32 (one MFMA per tile): s-slot mapping 0->0, 1->1, 2->3
    {
        short8 af2 = *reinterpret_cast<const short8*>(aB + (size_t)(m0 + lr) * 32 + lk * 8);
#pragma unroll
        for (int s = 0; s < 3; ++s) {
            int d = (s == 2) ? 3 : s;
#pragma unroll
            for (int t = 0; t < 4; ++t) {
                short8 bf = *reinterpret_cast<const short8*>(
                    Wi + (size_t)(s * 1024 + c0 + t * 16 + lr) * 32 + lk * 8);
                acc[d][t] = __builtin_amdgcn_mfma_f32_16x16x32_bf16(af2, bf, acc[d][t], 0, 0, 0);
            }
        }
    }

#pragma unroll
    for (int r = 0; r < 4; ++r) {
        int m = m0 + lk * 4 + r;
#pragma unroll
        for (int t = 0; t < 4; ++t) {
            int c = c0 + t * 16 + lr;
            float rr = sigmoidf_(acc[0][t][r] + dbh[c]        + dbi[c]);
            float zz = sigmoidf_(acc[1][t][r] + dbh[1024 + c] + dbi[1024 + c]);
            float nn = tanhf(acc[3][t][r] + dbi[2048 + c] + rr * (acc[2][t][r] + dbh[2048 + c]));
            float hid = bf2f(Hin[(size_t)m * 512 + (c & 511)]);
            Hout[(size_t)m * 1024 + c] = f2bf((1.0f - zz) * nn + zz * hid);
        }
    }
}

extern "C" void kernel_launch(void* const* d_in, const int* in_sizes, int n_in,
                              void* d_out, int out_size, void* d_ws, size_t ws_size,
                              hipStream_t stream) {
    const int*   symbols = (const int*)  d_in[0];
    const float* eps     = (const float*)d_in[1];
    const float* ewi     = (const float*)d_in[2];
    const float* ebi     = (const float*)d_in[3];
    const float* ewh     = (const float*)d_in[4];
    const float* ebh     = (const float*)d_in[5];
    const float* h2mu_w  = (const float*)d_in[6];
    const float* h2mu_b  = (const float*)d_in[7];
    const float* h2lv_w  = (const float*)d_in[8];
    const float* h2lv_b  = (const float*)d_in[9];
    const float* z2h_w   = (const float*)d_in[10];
    const float* z2h_b   = (const float*)d_in[11];
    const float* h2o_w   = (const float*)d_in[12];
    const float* h2o_b   = (const float*)d_in[13];
    const float* dwi     = (const float*)d_in[14];
    const float* dbi     = (const float*)d_in[15];
    const float* dwh     = (const float*)d_in[16];
    const float* dbh     = (const float*)d_in[17];

    float* out    = (float*)d_out;
    float* out_mu = out;
    float* out_lv = out + 256 * 128;
    float* out_pr = out + 2 * 256 * 128;

    // ---- workspace layout (bf16 states + bf16 weights, ~32.4 MB) ----
    u16* bufL  = (u16*)d_ws;                            // 16384*512
    u16* bufS  = bufL  + (size_t)16384 * 512;           //  8192*512
    u16* ewh_b = bufS  + (size_t)8192 * 512;            // 1536*1024
    u16* dwh_b = ewh_b + (size_t)1536 * 1024;           // 3072*512
    u16* dwi_b = dwh_b + (size_t)3072 * 512;            // 3072*32
    u16* aBuf  = dwi_b + (size_t)3072 * 32;             // 8192*32
    float* zlat = (float*)(aBuf + (size_t)8192 * 32);   // 256*128 f32

    // ---- weight conversion (independent; once per call) ----
    cvt_bf16<<<(1572864 + 255) / 256, 256, 0, stream>>>(ewh, ewh_b, 1572864);
    cvt_bf16<<<(1572864 + 255) / 256, 256, 0, stream>>>(dwh, dwh_b, 1572864);
    cvt_bf16<<<(98304 + 255) / 256, 256, 0, stream>>>(dwi, dwi_b, 98304);

    // ---- encoder ----
    enc_leaf<<<32768, 256, 0, stream>>>(ewi, ebi, ebh, symbols, bufL);
    const u16* src = bufL;
    u16*       dst = bufS;
    for (int d = 5; d >= 0; --d) {
        int M = 256 << d;
        enc_mfma<<<dim3(M / 64, 8), 256, 0, stream>>>(src, ewh_b, ewi, ebi, ebh, symbols,
                                                      dst, d, (1 << d) - 1);
        const u16* t = src; src = dst; dst = (u16*)t;
    }
    // root in bufL
    mid1<<<256, 256, 0, stream>>>(src, h2mu_w, h2mu_b, h2lv_w, h2lv_b, eps, zlat, out_mu, out_lv);
    mid2<<<256, 512, 0, stream>>>(zlat, z2h_w, z2h_b, bufL);   // hidden0 -> bufL

    // ---- decoder ---- parity: d4 fills bufS exactly, d5 fills bufL exactly
    const u16* hsrc = bufL;
    u16*       hdst = bufS;
    for (int d = 0; d < 6; ++d) {
        int M = 256 << d;
        dec_pred<<<M / 8, 256, 0, stream>>>(hsrc, h2o_w, h2o_b, aBuf, out_pr, d, (1 << d) - 1, 1);
        dec_mfma<<<dim3(M / 64, 16), 256, 0, stream>>>(hsrc, aBuf, dwh_b, dwi_b, dbh, dbi, hdst);
        const u16* t = hsrc; hsrc = hdst; hdst = (u16*)t;
    }
    dec_pred<<<16384 / 8, 256, 0, stream>>>(hsrc, h2o_w, h2o_b, aBuf, out_pr, 6, 63, 0);
}

// Round 7
// 723.826 us; speedup vs baseline: 4.9069x; 2.2530x over previous
//
#include <hip/hip_runtime.h>
#include <hip/hip_bf16.h>

typedef unsigned short u16;
typedef unsigned int u32;
typedef __attribute__((ext_vector_type(8))) short short8;   // 8 bf16 = 4 VGPR
typedef __attribute__((ext_vector_type(4))) float f32x4;

#define BK 32

__device__ __forceinline__ float sigmoidf_(float x) { return 1.0f / (1.0f + expf(-x)); }

__device__ __forceinline__ float bf2f(u16 u) {
    union { u32 i; float f; } v; v.i = ((u32)u) << 16; return v.f;
}
__device__ __forceinline__ u16 f2bf(float f) {
    union { float f; u32 i; } v; v.f = f;
    u32 lsb = (v.i >> 16) & 1u;
    v.i += 0x7fffu + lsb;            // RNE
    return (u16)(v.i >> 16);
}

// ---------------- f32 -> bf16 weight conversion ----------------
__global__ __launch_bounds__(256) void cvt_bf16(const float* __restrict__ src,
                                                u16* __restrict__ dst, int n)
{
    int i = blockIdx.x * 256 + threadIdx.x;
    if (i < n) dst[i] = f2bf(src[i]);
}

// ---------------- Encoder leaf (d=6) ----------------
__global__ __launch_bounds__(256) void enc_leaf(
    const float* __restrict__ ewi, const float* __restrict__ ebi,
    const float* __restrict__ ebh, const int* __restrict__ symbols,
    u16* __restrict__ hout)
{
    int idx = blockIdx.x * 256 + threadIdx.x;   // over 16384*512
    int c = idx & 511;
    int m = idx >> 9;
    int b = m >> 6, j = m & 63;
    int sym = symbols[b * 127 + 63 + j];
    float r = sigmoidf_(ewi[c * 32 + sym]          + ebi[c]        + ebh[c]);
    float z = sigmoidf_(ewi[(512 + c) * 32 + sym]  + ebi[512 + c]  + ebh[512 + c]);
    float n = tanhf(    ewi[(1024 + c) * 32 + sym] + ebi[1024 + c] + r * ebh[1024 + c]);
    hout[idx] = f2bf((1.0f - z) * n);
}

// ---------------- Encoder LDS-staged MFMA GEMM + GRU (levels d=5..0) ----------------
// A: (M,1024) bf16; W: ewh bf16 (1536,1024); hout: (M,512) bf16.
// grid=(M/64, 8), block=256 = 4 waves (2x2): wave tile 32 rows x 32 cols x 3 gates.
__global__ __launch_bounds__(256, 2) void enc_tile(
    const u16* __restrict__ A, const u16* __restrict__ W,
    const float* __restrict__ ewi, const float* __restrict__ ebi,
    const float* __restrict__ ebh, const int* __restrict__ symbols,
    u16* __restrict__ hout, int dlog, int node_base)
{
    __shared__ u16 Als[64 * BK];     // [row][k]  4 KB
    __shared__ u16 Bls[192 * BK];    // [rr][k]  12 KB  (rr = gate*64 + local col)
    const int tid  = threadIdx.x;
    const int lane = tid & 63;
    const int wid  = tid >> 6;
    const int wr = wid >> 1, wc = wid & 1;
    const int lr = lane & 15, lk = lane >> 4;
    const int m0 = blockIdx.x * 64;
    const int c0 = blockIdx.y * 64;

    // staging chunk assignment (16B chunks)
    const int arow = tid >> 2, akp = tid & 3;
    const size_t a_src = (size_t)(m0 + arow) * 1024 + akp * 8;
    u16* const a_dst = Als + arow * BK + akp * 8;
    size_t b_src[3]; u16* b_dst[3];
#pragma unroll
    for (int j = 0; j < 3; ++j) {
        int ch = tid + j * 256;
        int rr = ch >> 2, kp = ch & 3;
        int grow = (rr >> 6) * 512 + c0 + (rr & 63);
        b_src[j] = (size_t)grow * 1024 + kp * 8;
        b_dst[j] = Bls + rr * BK + kp * 8;
    }

    f32x4 acc[3][2][2];   // [gate][cfrag][rowfrag]
#pragma unroll
    for (int s = 0; s < 3; ++s)
#pragma unroll
        for (int cf = 0; cf < 2; ++cf)
#pragma unroll
            for (int i = 0; i < 2; ++i) acc[s][cf][i] = (f32x4){0.f, 0.f, 0.f, 0.f};

    // prologue: stage k0 = 0
    short8 sA = *reinterpret_cast<const short8*>(A + a_src);
    short8 sB0 = *reinterpret_cast<const short8*>(W + b_src[0]);
    short8 sB1 = *reinterpret_cast<const short8*>(W + b_src[1]);
    short8 sB2 = *reinterpret_cast<const short8*>(W + b_src[2]);
    *reinterpret_cast<short8*>(a_dst) = sA;
    *reinterpret_cast<short8*>(b_dst[0]) = sB0;
    *reinterpret_cast<short8*>(b_dst[1]) = sB1;
    *reinterpret_cast<short8*>(b_dst[2]) = sB2;
    __syncthreads();

    for (int k0 = 0;;) {
        const int nxt = k0 + BK;
        const bool more = (nxt < 1024);
        if (more) {   // early-issue next tile's global loads
            sA  = *reinterpret_cast<const short8*>(A + a_src + nxt);
            sB0 = *reinterpret_cast<const short8*>(W + b_src[0] + nxt);
            sB1 = *reinterpret_cast<const short8*>(W + b_src[1] + nxt);
            sB2 = *reinterpret_cast<const short8*>(W + b_src[2] + nxt);
        }
        // compute current tile
        short8 a0 = *reinterpret_cast<const short8*>(Als + (wr * 32 + lr) * BK + lk * 8);
        short8 a1 = *reinterpret_cast<const short8*>(Als + (wr * 32 + 16 + lr) * BK + lk * 8);
#pragma unroll
        for (int s = 0; s < 3; ++s)
#pragma unroll
            for (int cf = 0; cf < 2; ++cf) {
                short8 b = *reinterpret_cast<const short8*>(
                    Bls + (s * 64 + wc * 32 + cf * 16 + lr) * BK + lk * 8);
                acc[s][cf][0] = __builtin_amdgcn_mfma_f32_16x16x32_bf16(a0, b, acc[s][cf][0], 0, 0, 0);
                acc[s][cf][1] = __builtin_amdgcn_mfma_f32_16x16x32_bf16(a1, b, acc[s][cf][1], 0, 0, 0);
            }
        if (!more) break;
        __syncthreads();             // all waves done reading LDS
        *reinterpret_cast<short8*>(a_dst) = sA;
        *reinterpret_cast<short8*>(b_dst[0]) = sB0;
        *reinterpret_cast<short8*>(b_dst[1]) = sB1;
        *reinterpret_cast<short8*>(b_dst[2]) = sB2;
        __syncthreads();             // new tile visible
        k0 = nxt;
    }

    const int mask = (1 << dlog) - 1;
#pragma unroll
    for (int i = 0; i < 2; ++i)
#pragma unroll
        for (int r = 0; r < 4; ++r) {
            int m = m0 + wr * 32 + i * 16 + lk * 4 + r;
            int b_ = m >> dlog, j_ = m & mask;
            int sym = symbols[b_ * 127 + node_base + j_];
#pragma unroll
            for (int cf = 0; cf < 2; ++cf) {
                int c = c0 + wc * 32 + cf * 16 + lr;
                float rr_ = sigmoidf_(ewi[c * 32 + sym]          + ebi[c]        + acc[0][cf][i][r] + ebh[c]);
                float zz  = sigmoidf_(ewi[(512 + c) * 32 + sym]  + ebi[512 + c]  + acc[1][cf][i][r] + ebh[512 + c]);
                float nn  = tanhf(    ewi[(1024 + c) * 32 + sym] + ebi[1024 + c] + rr_ * (acc[2][cf][i][r] + ebh[1024 + c]));
                float hl = bf2f(A[(size_t)m * 1024 + c]);
                float hr = bf2f(A[(size_t)m * 1024 + 512 + c]);
                hout[(size_t)m * 512 + c] = f2bf((1.0f - zz) * nn + zz * (hl + hr) * 0.5f);
            }
        }
}

// ---------------- mid: mu/logvar/zlat ----------------
__global__ __launch_bounds__(256) void mid1(
    const u16* __restrict__ root, const float* __restrict__ h2mu_w,
    const float* __restrict__ h2mu_b, const float* __restrict__ h2lv_w,
    const float* __restrict__ h2lv_b, const float* __restrict__ eps,
    float* __restrict__ zlat, float* __restrict__ out_mu,
    float* __restrict__ out_lv)
{
    int b = blockIdx.x, t = threadIdx.x;
    __shared__ float rs[512];
    rs[t]       = bf2f(root[(size_t)b * 512 + t]);
    rs[t + 256] = bf2f(root[(size_t)b * 512 + t + 256]);
    __syncthreads();
    const float* w = (t < 128) ? (h2mu_w + (size_t)t * 512) : (h2lv_w + (size_t)(t - 128) * 512);
    float acc = 0.0f;
    for (int k = 0; k < 512; ++k) acc += rs[k] * w[k];
    acc += (t < 128) ? h2mu_b[t] : h2lv_b[t - 128];
    __shared__ float vals[256];
    vals[t] = acc;
    __syncthreads();
    if (t < 128) {
        float mu = vals[t], lv = vals[t + 128];
        float zl = mu + eps[b * 128 + t] * expf(0.5f * lv);
        zlat[b * 128 + t] = zl;
        out_mu[b * 128 + t] = mu;
        out_lv[b * 128 + t] = lv;
    }
}

__global__ __launch_bounds__(512) void mid2(
    const float* __restrict__ zlat, const float* __restrict__ z2h_w,
    const float* __restrict__ z2h_b, u16* __restrict__ hidden)
{
    int b = blockIdx.x, t = threadIdx.x;
    __shared__ float zs[128];
    if (t < 128) zs[t] = zlat[b * 128 + t];
    __syncthreads();
    float acc = z2h_b[t];
    for (int k = 0; k < 128; ++k) acc += zs[k] * z2h_w[(size_t)t * 128 + k];
    hidden[(size_t)b * 512 + t] = f2bf(acc);
}

// ---------------- decoder: pred + softmax (8 rows x 32 lanes) ----------------
__global__ __launch_bounds__(256) void dec_pred(
    const u16* __restrict__ hidden, const float* __restrict__ h2o_w,
    const float* __restrict__ h2o_b, u16* __restrict__ aout,
    float* __restrict__ preds_out, int dlog, int node_base, int write_a)
{
    int tid = threadIdx.x;
    int s = tid & 31, r = tid >> 5;
    __shared__ float hs[8][512];
    {
        const uint4* src4 = reinterpret_cast<const uint4*>(hidden + (size_t)blockIdx.x * 4096);
#pragma unroll
        for (int it = 0; it < 2; ++it) {
            int q = it * 256 + tid;            // [0,512)
            uint4 u = src4[q];
            int base = q * 8;
            int rr = base >> 9, cc = base & 511;
            hs[rr][cc + 0] = bf2f((u16)(u.x & 0xffff)); hs[rr][cc + 1] = bf2f((u16)(u.x >> 16));
            hs[rr][cc + 2] = bf2f((u16)(u.y & 0xffff)); hs[rr][cc + 3] = bf2f((u16)(u.y >> 16));
            hs[rr][cc + 4] = bf2f((u16)(u.z & 0xffff)); hs[rr][cc + 5] = bf2f((u16)(u.z >> 16));
            hs[rr][cc + 6] = bf2f((u16)(u.w & 0xffff)); hs[rr][cc + 7] = bf2f((u16)(u.w >> 16));
        }
    }
    __syncthreads();
    const float4* wrow = reinterpret_cast<const float4*>(h2o_w + (size_t)s * 512);
    const float4* hrow = reinterpret_cast<const float4*>(&hs[r][0]);
    float acc = 0.0f;
#pragma unroll 8
    for (int k = 0; k < 128; ++k) {
        float4 w = wrow[k], h = hrow[k];
        acc += w.x * h.x + w.y * h.y + w.z * h.z + w.w * h.w;
    }
    acc += h2o_b[s];
    float mx = acc;
#pragma unroll
    for (int off = 16; off; off >>= 1) mx = fmaxf(mx, __shfl_xor(mx, off, 32));
    float e = expf(acc - mx);
    float sum = e;
#pragma unroll
    for (int off = 16; off; off >>= 1) sum += __shfl_xor(sum, off, 32);
    float a = e / sum;

    int m = blockIdx.x * 8 + r;
    int b = m >> dlog;
    int j = m & ((1 << dlog) - 1);
    preds_out[(size_t)(b * 127 + node_base + j) * 32 + s] = acc;
    if (write_a) aout[(size_t)m * 32 + s] = f2bf(a);
}

// ---------------- decoder LDS-staged MFMA GRU (levels d=0..5) ----------------
// Hin: (M,512) bf16; aB: (M,32) bf16; Wh: dwh bf16 (3072,512); Wi: dwi bf16 (3072,32);
// Hout: (M,1024) bf16. grid=(M/64, 16), block=256.
// acc[0]=r (Wh+Wi), acc[1]=z (Wh+Wi), acc[2]=gh_n (Wh), acc[3]=gi_n (Wi)
__global__ __launch_bounds__(256, 2) void dec_tile(
    const u16* __restrict__ Hin, const u16* __restrict__ aB,
    const u16* __restrict__ Wh, const u16* __restrict__ Wi,
    const float* __restrict__ dbh, const float* __restrict__ dbi,
    u16* __restrict__ Hout)
{
    __shared__ u16 Als[64 * BK];
    __shared__ u16 Bls[192 * BK];
    const int tid  = threadIdx.x;
    const int lane = tid & 63;
    const int wid  = tid >> 6;
    const int wr = wid >> 1, wc = wid & 1;
    const int lr = lane & 15, lk = lane >> 4;
    const int m0 = blockIdx.x * 64;
    const int c0 = blockIdx.y * 64;      // within 1024

    const int arow = tid >> 2, akp = tid & 3;
    const size_t a_src = (size_t)(m0 + arow) * 512 + akp * 8;
    u16* const a_dst = Als + arow * BK + akp * 8;
    size_t b_src[3]; u16* b_dst[3];
#pragma unroll
    for (int j = 0; j < 3; ++j) {
        int ch = tid + j * 256;
        int rr = ch >> 2, kp = ch & 3;
        int grow = (rr >> 6) * 1024 + c0 + (rr & 63);
        b_src[j] = (size_t)grow * 512 + kp * 8;
        b_dst[j] = Bls + rr * BK + kp * 8;
    }

    f32x4 acc[4][2][2];
#pragma unroll
    for (int s = 0; s < 4; ++s)
#pragma unroll
        for (int cf = 0; cf < 2; ++cf)
#pragma unroll
            for (int i = 0; i < 2; ++i) acc[s][cf][i] = (f32x4){0.f, 0.f, 0.f, 0.f};

    short8 sA  = *reinterpret_cast<const short8*>(Hin + a_src);
    short8 sB0 = *reinterpret_cast<const short8*>(Wh + b_src[0]);
    short8 sB1 = *reinterpret_cast<const short8*>(Wh + b_src[1]);
    short8 sB2 = *reinterpret_cast<const short8*>(Wh + b_src[2]);
    *reinterpret_cast<short8*>(a_dst) = sA;
    *reinterpret_cast<short8*>(b_dst[0]) = sB0;
    *reinterpret_cast<short8*>(b_dst[1]) = sB1;
    *reinterpret_cast<short8*>(b_dst[2]) = sB2;
    __syncthreads();

    for (int k0 = 0;;) {
        const int nxt = k0 + BK;
        const bool more = (nxt < 512);
        if (more) {
            sA  = *reinterpret_cast<const short8*>(Hin + a_src + nxt);
            sB0 = *reinterpret_cast<const short8*>(Wh + b_src[0] + nxt);
            sB1 = *reinterpret_cast<const short8*>(Wh + b_src[1] + nxt);
            sB2 = *reinterpret_cast<const short8*>(Wh + b_src[2] + nxt);
        }
        short8 a0 = *reinterpret_cast<const short8*>(Als + (wr * 32 + lr) * BK + lk * 8);
        short8 a1 = *reinterpret_cast<const short8*>(Als + (wr * 32 + 16 + lr) * BK + lk * 8);
#pragma unroll
        for (int s = 0; s < 3; ++s)
#pragma unroll
            for (int cf = 0; cf < 2; ++cf) {
                short8 b = *reinterpret_cast<const short8*>(
                    Bls + (s * 64 + wc * 32 + cf * 16 + lr) * BK + lk * 8);
                acc[s][cf][0] = __builtin_amdgcn_mfma_f32_16x16x32_bf16(a0, b, acc[s][cf][0], 0, 0, 0);
                acc[s][cf][1] = __builtin_amdgcn_mfma_f32_16x16x32_bf16(a1, b, acc[s][cf][1], 0, 0, 0);
            }
        if (!more) break;
        __syncthreads();
        *reinterpret_cast<short8*>(a_dst) = sA;
        *reinterpret_cast<short8*>(b_dst[0]) = sB0;
        *reinterpret_cast<short8*>(b_dst[1]) = sB1;
        *reinterpret_cast<short8*>(b_dst[2]) = sB2;
        __syncthreads();
        k0 = nxt;
    }

    // rank-32 input-gate contribution straight from global (small)
    {
        short8 a0w = *reinterpret_cast<const short8*>(aB + (size_t)(m0 + wr * 32 + lr) * 32 + lk * 8);
        short8 a1w = *reinterpret_cast<const short8*>(aB + (size_t)(m0 + wr * 32 + 16 + lr) * 32 + lk * 8);
#pragma unroll
        for (int s = 0; s < 3; ++s) {
            const int d = (s == 2) ? 3 : s;
#pragma unroll
            for (int cf = 0; cf < 2; ++cf) {
                short8 b = *reinterpret_cast<const short8*>(
                    Wi + (size_t)(s * 1024 + c0 + wc * 32 + cf * 16 + lr) * 32 + lk * 8);
                acc[d][cf][0] = __builtin_amdgcn_mfma_f32_16x16x32_bf16(a0w, b, acc[d][cf][0], 0, 0, 0);
                acc[d][cf][1] = __builtin_amdgcn_mfma_f32_16x16x32_bf16(a1w, b, acc[d][cf][1], 0, 0, 0);
            }
        }
    }

#pragma unroll
    for (int i = 0; i < 2; ++i)
#pragma unroll
        for (int r = 0; r < 4; ++r) {
            int m = m0 + wr * 32 + i * 16 + lk * 4 + r;
#pragma unroll
            for (int cf = 0; cf < 2; ++cf) {
                int c = c0 + wc * 32 + cf * 16 + lr;
                float rr_ = sigmoidf_(acc[0][cf][i][r] + dbh[c]        + dbi[c]);
                float zz  = sigmoidf_(acc[1][cf][i][r] + dbh[1024 + c] + dbi[1024 + c]);
                float nn  = tanhf(acc[3][cf][i][r] + dbi[2048 + c] + rr_ * (acc[2][cf][i][r] + dbh[2048 + c]));
                float hid = bf2f(Hin[(size_t)m * 512 + (c & 511)]);
                Hout[(size_t)m * 1024 + c] = f2bf((1.0f - zz) * nn + zz * hid);
            }
        }
}

extern "C" void kernel_launch(void* const* d_in, const int* in_sizes, int n_in,
                              void* d_out, int out_size, void* d_ws, size_t ws_size,
                              hipStream_t stream) {
    const int*   symbols = (const int*)  d_in[0];
    const float* eps     = (const float*)d_in[1];
    const float* ewi     = (const float*)d_in[2];
    const float* ebi     = (const float*)d_in[3];
    const float* ewh     = (const float*)d_in[4];
    const float* ebh     = (const float*)d_in[5];
    const float* h2mu_w  = (const float*)d_in[6];
    const float* h2mu_b  = (const float*)d_in[7];
    const float* h2lv_w  = (const float*)d_in[8];
    const float* h2lv_b  = (const float*)d_in[9];
    const float* z2h_w   = (const float*)d_in[10];
    const float* z2h_b   = (const float*)d_in[11];
    const float* h2o_w   = (const float*)d_in[12];
    const float* h2o_b   = (const float*)d_in[13];
    const float* dwi     = (const float*)d_in[14];
    const float* dbi     = (const float*)d_in[15];
    const float* dwh     = (const float*)d_in[16];
    const float* dbh     = (const float*)d_in[17];

    float* out    = (float*)d_out;
    float* out_mu = out;
    float* out_lv = out + 256 * 128;
    float* out_pr = out + 2 * 256 * 128;

    // ---- workspace layout (bf16 states + bf16 weights, ~32.4 MB) ----
    u16* bufL  = (u16*)d_ws;                            // 16384*512
    u16* bufS  = bufL  + (size_t)16384 * 512;           //  8192*512
    u16* ewh_b = bufS  + (size_t)8192 * 512;            // 1536*1024
    u16* dwh_b = ewh_b + (size_t)1536 * 1024;           // 3072*512
    u16* dwi_b = dwh_b + (size_t)3072 * 512;            // 3072*32
    u16* aBuf  = dwi_b + (size_t)3072 * 32;             // 8192*32
    float* zlat = (float*)(aBuf + (size_t)8192 * 32);   // 256*128 f32

    // ---- weight conversion (once per call) ----
    cvt_bf16<<<(1572864 + 255) / 256, 256, 0, stream>>>(ewh, ewh_b, 1572864);
    cvt_bf16<<<(1572864 + 255) / 256, 256, 0, stream>>>(dwh, dwh_b, 1572864);
    cvt_bf16<<<(98304 + 255) / 256, 256, 0, stream>>>(dwi, dwi_b, 98304);

    // ---- encoder ----
    enc_leaf<<<32768, 256, 0, stream>>>(ewi, ebi, ebh, symbols, bufL);
    const u16* src = bufL;
    u16*       dst = bufS;
    for (int d = 5; d >= 0; --d) {
        int M = 256 << d;
        enc_tile<<<dim3(M / 64, 8), 256, 0, stream>>>(src, ewh_b, ewi, ebi, ebh, symbols,
                                                      dst, d, (1 << d) - 1);
        const u16* t = src; src = dst; dst = (u16*)t;
    }
    // root in bufL
    mid1<<<256, 256, 0, stream>>>(src, h2mu_w, h2mu_b, h2lv_w, h2lv_b, eps, zlat, out_mu, out_lv);
    mid2<<<256, 512, 0, stream>>>(zlat, z2h_w, z2h_b, bufL);   // hidden0 -> bufL

    // ---- decoder ---- parity: d4 fills bufS exactly, d5 fills bufL exactly
    const u16* hsrc = bufL;
    u16*       hdst = bufS;
    for (int d = 0; d < 6; ++d) {
        int M = 256 << d;
        dec_pred<<<M / 8, 256, 0, stream>>>(hsrc, h2o_w, h2o_b, aBuf, out_pr, d, (1 << d) - 1, 1);
        dec_tile<<<dim3(M / 64, 16), 256, 0, stream>>>(hsrc, aBuf, dwh_b, dwi_b, dbh, dbi, hdst);
        const u16* t = hsrc; hsrc = hdst; hdst = (u16*)t;
    }
    dec_pred<<<16384 / 8, 256, 0, stream>>>(hsrc, h2o_w, h2o_b, aBuf, out_pr, 6, 63, 0);
}

// Round 8
// 431.311 us; speedup vs baseline: 8.2347x; 1.6782x over previous
//
#include <hip/hip_runtime.h>
#include <hip/hip_bf16.h>

typedef unsigned short u16;
typedef unsigned int u32;
typedef __attribute__((ext_vector_type(8))) short short8;   // 8 bf16 = 4 VGPR
typedef __attribute__((ext_vector_type(4))) float f32x4;

#define BK 32

__device__ __forceinline__ float sigmoidf_(float x) { return 1.0f / (1.0f + expf(-x)); }

__device__ __forceinline__ float bf2f(u16 u) {
    union { u32 i; float f; } v; v.i = ((u32)u) << 16; return v.f;
}
__device__ __forceinline__ u16 f2bf(float f) {
    union { float f; u32 i; } v; v.f = f;
    u32 lsb = (v.i >> 16) & 1u;
    v.i += 0x7fffu + lsb;            // RNE
    return (u16)(v.i >> 16);
}

// ---------------- f32 -> bf16 weight conversion ----------------
__global__ __launch_bounds__(256) void cvt_bf16(const float* __restrict__ src,
                                                u16* __restrict__ dst, int n)
{
    int i = blockIdx.x * 256 + threadIdx.x;
    if (i < n) dst[i] = f2bf(src[i]);
}

// ---------------- leaf table: tab[sym][c], 32x512 ----------------
__global__ __launch_bounds__(256) void leaf_tab(
    const float* __restrict__ ewi, const float* __restrict__ ebi,
    const float* __restrict__ ebh, u16* __restrict__ tab)
{
    int idx = blockIdx.x * 256 + threadIdx.x;   // 32*512
    int c = idx & 511;
    int sym = idx >> 9;
    float r = sigmoidf_(ewi[c * 32 + sym]          + ebi[c]        + ebh[c]);
    float z = sigmoidf_(ewi[(512 + c) * 32 + sym]  + ebi[512 + c]  + ebh[512 + c]);
    float n = tanhf(    ewi[(1024 + c) * 32 + sym] + ebi[1024 + c] + r * ebh[1024 + c]);
    tab[idx] = f2bf((1.0f - z) * n);
}

// ---------------- Encoder leaf (d=6): gather from table ----------------
__global__ __launch_bounds__(256) void enc_leaf(
    const u16* __restrict__ tab, const int* __restrict__ symbols,
    u16* __restrict__ hout)
{
    int t = blockIdx.x * 256 + threadIdx.x;     // over 16384*64 (8 elems each)
    int m = t >> 6, c0 = (t & 63) * 8;
    int sym = symbols[(m >> 6) * 127 + 63 + (m & 63)];
    *reinterpret_cast<short8*>(hout + (size_t)m * 512 + c0) =
        *reinterpret_cast<const short8*>(tab + sym * 512 + c0);
}

// ---------------- Encoder LDS-staged MFMA GEMM + GRU (levels d=5..0) ----------------
__global__ __launch_bounds__(256, 2) void enc_tile(
    const u16* __restrict__ A, const u16* __restrict__ W,
    const float* __restrict__ ewi, const float* __restrict__ ebi,
    const float* __restrict__ ebh, const int* __restrict__ symbols,
    u16* __restrict__ hout, int dlog, int node_base)
{
    __shared__ u16 Als[64 * BK];
    __shared__ u16 Bls[192 * BK];
    const int tid  = threadIdx.x;
    const int lane = tid & 63;
    const int wid  = tid >> 6;
    const int wr = wid >> 1, wc = wid & 1;
    const int lr = lane & 15, lk = lane >> 4;
    const int m0 = blockIdx.x * 64;
    const int c0 = blockIdx.y * 64;

    const int arow = tid >> 2, akp = tid & 3;
    const size_t a_src = (size_t)(m0 + arow) * 1024 + akp * 8;
    u16* const a_dst = Als + arow * BK + akp * 8;
    size_t b_src[3]; u16* b_dst[3];
#pragma unroll
    for (int j = 0; j < 3; ++j) {
        int ch = tid + j * 256;
        int rr = ch >> 2, kp = ch & 3;
        int grow = (rr >> 6) * 512 + c0 + (rr & 63);
        b_src[j] = (size_t)grow * 1024 + kp * 8;
        b_dst[j] = Bls + rr * BK + kp * 8;
    }

    f32x4 acc[3][2][2];
#pragma unroll
    for (int s = 0; s < 3; ++s)
#pragma unroll
        for (int cf = 0; cf < 2; ++cf)
#pragma unroll
            for (int i = 0; i < 2; ++i) acc[s][cf][i] = (f32x4){0.f, 0.f, 0.f, 0.f};

    short8 sA = *reinterpret_cast<const short8*>(A + a_src);
    short8 sB0 = *reinterpret_cast<const short8*>(W + b_src[0]);
    short8 sB1 = *reinterpret_cast<const short8*>(W + b_src[1]);
    short8 sB2 = *reinterpret_cast<const short8*>(W + b_src[2]);
    *reinterpret_cast<short8*>(a_dst) = sA;
    *reinterpret_cast<short8*>(b_dst[0]) = sB0;
    *reinterpret_cast<short8*>(b_dst[1]) = sB1;
    *reinterpret_cast<short8*>(b_dst[2]) = sB2;
    __syncthreads();

    for (int k0 = 0;;) {
        const int nxt = k0 + BK;
        const bool more = (nxt < 1024);
        if (more) {
            sA  = *reinterpret_cast<const short8*>(A + a_src + nxt);
            sB0 = *reinterpret_cast<const short8*>(W + b_src[0] + nxt);
            sB1 = *reinterpret_cast<const short8*>(W + b_src[1] + nxt);
            sB2 = *reinterpret_cast<const short8*>(W + b_src[2] + nxt);
        }
        short8 a0 = *reinterpret_cast<const short8*>(Als + (wr * 32 + lr) * BK + lk * 8);
        short8 a1 = *reinterpret_cast<const short8*>(Als + (wr * 32 + 16 + lr) * BK + lk * 8);
#pragma unroll
        for (int s = 0; s < 3; ++s)
#pragma unroll
            for (int cf = 0; cf < 2; ++cf) {
                short8 b = *reinterpret_cast<const short8*>(
                    Bls + (s * 64 + wc * 32 + cf * 16 + lr) * BK + lk * 8);
                acc[s][cf][0] = __builtin_amdgcn_mfma_f32_16x16x32_bf16(a0, b, acc[s][cf][0], 0, 0, 0);
                acc[s][cf][1] = __builtin_amdgcn_mfma_f32_16x16x32_bf16(a1, b, acc[s][cf][1], 0, 0, 0);
            }
        if (!more) break;
        __syncthreads();
        *reinterpret_cast<short8*>(a_dst) = sA;
        *reinterpret_cast<short8*>(b_dst[0]) = sB0;
        *reinterpret_cast<short8*>(b_dst[1]) = sB1;
        *reinterpret_cast<short8*>(b_dst[2]) = sB2;
        __syncthreads();
        k0 = nxt;
    }

    const int mask = (1 << dlog) - 1;
#pragma unroll
    for (int i = 0; i < 2; ++i)
#pragma unroll
        for (int r = 0; r < 4; ++r) {
            int m = m0 + wr * 32 + i * 16 + lk * 4 + r;
            int b_ = m >> dlog, j_ = m & mask;
            int sym = symbols[b_ * 127 + node_base + j_];
#pragma unroll
            for (int cf = 0; cf < 2; ++cf) {
                int c = c0 + wc * 32 + cf * 16 + lr;
                float rr_ = sigmoidf_(ewi[c * 32 + sym]          + ebi[c]        + acc[0][cf][i][r] + ebh[c]);
                float zz  = sigmoidf_(ewi[(512 + c) * 32 + sym]  + ebi[512 + c]  + acc[1][cf][i][r] + ebh[512 + c]);
                float nn  = tanhf(    ewi[(1024 + c) * 32 + sym] + ebi[1024 + c] + rr_ * (acc[2][cf][i][r] + ebh[1024 + c]));
                float hl = bf2f(A[(size_t)m * 1024 + c]);
                float hr = bf2f(A[(size_t)m * 1024 + 512 + c]);
                hout[(size_t)m * 512 + c] = f2bf((1.0f - zz) * nn + zz * (hl + hr) * 0.5f);
            }
        }
}

// ---------------- mid: mu/logvar/zlat ----------------
__global__ __launch_bounds__(256) void mid1(
    const u16* __restrict__ root, const float* __restrict__ h2mu_w,
    const float* __restrict__ h2mu_b, const float* __restrict__ h2lv_w,
    const float* __restrict__ h2lv_b, const float* __restrict__ eps,
    float* __restrict__ zlat, float* __restrict__ out_mu,
    float* __restrict__ out_lv)
{
    int b = blockIdx.x, t = threadIdx.x;
    __shared__ float rs[512];
    rs[t]       = bf2f(root[(size_t)b * 512 + t]);
    rs[t + 256] = bf2f(root[(size_t)b * 512 + t + 256]);
    __syncthreads();
    const float* w = (t < 128) ? (h2mu_w + (size_t)t * 512) : (h2lv_w + (size_t)(t - 128) * 512);
    float acc = 0.0f;
    for (int k = 0; k < 512; ++k) acc += rs[k] * w[k];
    acc += (t < 128) ? h2mu_b[t] : h2lv_b[t - 128];
    __shared__ float vals[256];
    vals[t] = acc;
    __syncthreads();
    if (t < 128) {
        float mu = vals[t], lv = vals[t + 128];
        float zl = mu + eps[b * 128 + t] * expf(0.5f * lv);
        zlat[b * 128 + t] = zl;
        out_mu[b * 128 + t] = mu;
        out_lv[b * 128 + t] = lv;
    }
}

__global__ __launch_bounds__(512) void mid2(
    const float* __restrict__ zlat, const float* __restrict__ z2h_w,
    const float* __restrict__ z2h_b, u16* __restrict__ hidden)
{
    int b = blockIdx.x, t = threadIdx.x;
    __shared__ float zs[128];
    if (t < 128) zs[t] = zlat[b * 128 + t];
    __syncthreads();
    float acc = z2h_b[t];
    for (int k = 0; k < 128; ++k) acc += zs[k] * z2h_w[(size_t)t * 128 + k];
    hidden[(size_t)b * 512 + t] = f2bf(acc);
}

// ---------------- decoder pred via MFMA + in-register softmax ----------------
// hidden (M,512) bf16 x Wo (32,512) bf16 -> pred (M,32); 4 waves x 16 rows per block.
__global__ __launch_bounds__(256) void pred_mfma(
    const u16* __restrict__ hidden, const u16* __restrict__ Wo,
    const float* __restrict__ h2o_b, u16* __restrict__ aout,
    float* __restrict__ preds_out, int dlog, int node_base, int write_a)
{
    const int lane = threadIdx.x & 63;
    const int wid  = threadIdx.x >> 6;
    const int lr = lane & 15, lk = lane >> 4;
    const int m0 = blockIdx.x * 64 + wid * 16;

    f32x4 acc0 = (f32x4){0.f, 0.f, 0.f, 0.f};
    f32x4 acc1 = (f32x4){0.f, 0.f, 0.f, 0.f};
    const u16* Arow = hidden + (size_t)(m0 + lr) * 512 + lk * 8;
    const u16* B0 = Wo + (size_t)lr * 512 + lk * 8;
    const u16* B1 = Wo + (size_t)(16 + lr) * 512 + lk * 8;
#pragma unroll
    for (int k0 = 0; k0 < 512; k0 += 32) {
        short8 a  = *reinterpret_cast<const short8*>(Arow + k0);
        short8 b0 = *reinterpret_cast<const short8*>(B0 + k0);
        short8 b1 = *reinterpret_cast<const short8*>(B1 + k0);
        acc0 = __builtin_amdgcn_mfma_f32_16x16x32_bf16(a, b0, acc0, 0, 0, 0);
        acc1 = __builtin_amdgcn_mfma_f32_16x16x32_bf16(a, b1, acc1, 0, 0, 0);
    }
    const float bb0 = h2o_b[lr], bb1 = h2o_b[16 + lr];
    const int dmask = (1 << dlog) - 1;
#pragma unroll
    for (int r = 0; r < 4; ++r) {
        float p0 = acc0[r] + bb0;
        float p1 = acc1[r] + bb1;
        float mx = fmaxf(p0, p1);
#pragma unroll
        for (int off = 1; off < 16; off <<= 1) mx = fmaxf(mx, __shfl_xor(mx, off));
        float e0 = expf(p0 - mx), e1 = expf(p1 - mx);
        float s = e0 + e1;
#pragma unroll
        for (int off = 1; off < 16; off <<= 1) s += __shfl_xor(s, off);
        int m = m0 + lk * 4 + r;
        int b_ = m >> dlog, j_ = m & dmask;
        size_t o = (size_t)(b_ * 127 + node_base + j_) * 32;
        preds_out[o + lr] = p0;
        preds_out[o + 16 + lr] = p1;
        if (write_a) {
            float inv = 1.0f / s;
            aout[(size_t)m * 32 + lr]      = f2bf(e0 * inv);
            aout[(size_t)m * 32 + 16 + lr] = f2bf(e1 * inv);
        }
    }
}

// ---------------- decoder LDS-staged MFMA GRU (levels d=0..5) ----------------
__global__ __launch_bounds__(256, 2) void dec_tile(
    const u16* __restrict__ Hin, const u16* __restrict__ aB,
    const u16* __restrict__ Wh, const u16* __restrict__ Wi,
    const float* __restrict__ dbh, const float* __restrict__ dbi,
    u16* __restrict__ Hout)
{
    __shared__ u16 Als[64 * BK];
    __shared__ u16 Bls[192 * BK];
    const int tid  = threadIdx.x;
    const int lane = tid & 63;
    const int wid  = tid >> 6;
    const int wr = wid >> 1, wc = wid & 1;
    const int lr = lane & 15, lk = lane >> 4;
    const int m0 = blockIdx.x * 64;
    const int c0 = blockIdx.y * 64;

    const int arow = tid >> 2, akp = tid & 3;
    const size_t a_src = (size_t)(m0 + arow) * 512 + akp * 8;
    u16* const a_dst = Als + arow * BK + akp * 8;
    size_t b_src[3]; u16* b_dst[3];
#pragma unroll
    for (int j = 0; j < 3; ++j) {
        int ch = tid + j * 256;
        int rr = ch >> 2, kp = ch & 3;
        int grow = (rr >> 6) * 1024 + c0 + (rr & 63);
        b_src[j] = (size_t)grow * 512 + kp * 8;
        b_dst[j] = Bls + rr * BK + kp * 8;
    }

    f32x4 acc[4][2][2];
#pragma unroll
    for (int s = 0; s < 4; ++s)
#pragma unroll
        for (int cf = 0; cf < 2; ++cf)
#pragma unroll
            for (int i = 0; i < 2; ++i) acc[s][cf][i] = (f32x4){0.f, 0.f, 0.f, 0.f};

    short8 sA  = *reinterpret_cast<const short8*>(Hin + a_src);
    short8 sB0 = *reinterpret_cast<const short8*>(Wh + b_src[0]);
    short8 sB1 = *reinterpret_cast<const short8*>(Wh + b_src[1]);
    short8 sB2 = *reinterpret_cast<const short8*>(Wh + b_src[2]);
    *reinterpret_cast<short8*>(a_dst) = sA;
    *reinterpret_cast<short8*>(b_dst[0]) = sB0;
    *reinterpret_cast<short8*>(b_dst[1]) = sB1;
    *reinterpret_cast<short8*>(b_dst[2]) = sB2;
    __syncthreads();

    for (int k0 = 0;;) {
        const int nxt = k0 + BK;
        const bool more = (nxt < 512);
        if (more) {
            sA  = *reinterpret_cast<const short8*>(Hin + a_src + nxt);
            sB0 = *reinterpret_cast<const short8*>(Wh + b_src[0] + nxt);
            sB1 = *reinterpret_cast<const short8*>(Wh + b_src[1] + nxt);
            sB2 = *reinterpret_cast<const short8*>(Wh + b_src[2] + nxt);
        }
        short8 a0 = *reinterpret_cast<const short8*>(Als + (wr * 32 + lr) * BK + lk * 8);
        short8 a1 = *reinterpret_cast<const short8*>(Als + (wr * 32 + 16 + lr) * BK + lk * 8);
#pragma unroll
        for (int s = 0; s < 3; ++s)
#pragma unroll
            for (int cf = 0; cf < 2; ++cf) {
                short8 b = *reinterpret_cast<const short8*>(
                    Bls + (s * 64 + wc * 32 + cf * 16 + lr) * BK + lk * 8);
                acc[s][cf][0] = __builtin_amdgcn_mfma_f32_16x16x32_bf16(a0, b, acc[s][cf][0], 0, 0, 0);
                acc[s][cf][1] = __builtin_amdgcn_mfma_f32_16x16x32_bf16(a1, b, acc[s][cf][1], 0, 0, 0);
            }
        if (!more) break;
        __syncthreads();
        *reinterpret_cast<short8*>(a_dst) = sA;
        *reinterpret_cast<short8*>(b_dst[0]) = sB0;
        *reinterpret_cast<short8*>(b_dst[1]) = sB1;
        *reinterpret_cast<short8*>(b_dst[2]) = sB2;
        __syncthreads();
        k0 = nxt;
    }

    {
        short8 a0w = *reinterpret_cast<const short8*>(aB + (size_t)(m0 + wr * 32 + lr) * 32 + lk * 8);
        short8 a1w = *reinterpret_cast<const short8*>(aB + (size_t)(m0 + wr * 32 + 16 + lr) * 32 + lk * 8);
#pragma unroll
        for (int s = 0; s < 3; ++s) {
            const int d = (s == 2) ? 3 : s;
#pragma unroll
            for (int cf = 0; cf < 2; ++cf) {
                short8 b = *reinterpret_cast<const short8*>(
                    Wi + (size_t)(s * 1024 + c0 + wc * 32 + cf * 16 + lr) * 32 + lk * 8);
                acc[d][cf][0] = __builtin_amdgcn_mfma_f32_16x16x32_bf16(a0w, b, acc[d][cf][0], 0, 0, 0);
                acc[d][cf][1] = __builtin_amdgcn_mfma_f32_16x16x32_bf16(a1w, b, acc[d][cf][1], 0, 0, 0);
            }
        }
    }

#pragma unroll
    for (int i = 0; i < 2; ++i)
#pragma unroll
        for (int r = 0; r < 4; ++r) {
            int m = m0 + wr * 32 + i * 16 + lk * 4 + r;
#pragma unroll
            for (int cf = 0; cf < 2; ++cf) {
                int c = c0 + wc * 32 + cf * 16 + lr;
                float rr_ = sigmoidf_(acc[0][cf][i][r] + dbh[c]        + dbi[c]);
                float zz  = sigmoidf_(acc[1][cf][i][r] + dbh[1024 + c] + dbi[1024 + c]);
                float nn  = tanhf(acc[3][cf][i][r] + dbi[2048 + c] + rr_ * (acc[2][cf][i][r] + dbh[2048 + c]));
                float hid = bf2f(Hin[(size_t)m * 512 + (c & 511)]);
                Hout[(size_t)m * 1024 + c] = f2bf((1.0f - zz) * nn + zz * hid);
            }
        }
}

extern "C" void kernel_launch(void* const* d_in, const int* in_sizes, int n_in,
                              void* d_out, int out_size, void* d_ws, size_t ws_size,
                              hipStream_t stream) {
    const int*   symbols = (const int*)  d_in[0];
    const float* eps     = (const float*)d_in[1];
    const float* ewi     = (const float*)d_in[2];
    const float* ebi     = (const float*)d_in[3];
    const float* ewh     = (const float*)d_in[4];
    const float* ebh     = (const float*)d_in[5];
    const float* h2mu_w  = (const float*)d_in[6];
    const float* h2mu_b  = (const float*)d_in[7];
    const float* h2lv_w  = (const float*)d_in[8];
    const float* h2lv_b  = (const float*)d_in[9];
    const float* z2h_w   = (const float*)d_in[10];
    const float* z2h_b   = (const float*)d_in[11];
    const float* h2o_w   = (const float*)d_in[12];
    const float* h2o_b   = (const float*)d_in[13];
    const float* dwi     = (const float*)d_in[14];
    const float* dbi     = (const float*)d_in[15];
    const float* dwh     = (const float*)d_in[16];
    const float* dbh     = (const float*)d_in[17];

    float* out    = (float*)d_out;
    float* out_mu = out;
    float* out_lv = out + 256 * 128;
    float* out_pr = out + 2 * 256 * 128;

    // ---- workspace layout (~32.4 MB) ----
    u16* bufL  = (u16*)d_ws;                            // 16384*512
    u16* bufS  = bufL  + (size_t)16384 * 512;           //  8192*512
    u16* ewh_b = bufS  + (size_t)8192 * 512;            // 1536*1024
    u16* dwh_b = ewh_b + (size_t)1536 * 1024;           // 3072*512
    u16* dwi_b = dwh_b + (size_t)3072 * 512;            // 3072*32
    u16* wo_b  = dwi_b + (size_t)3072 * 32;             // 32*512
    u16* ltab  = wo_b  + (size_t)32 * 512;              // 32*512
    u16* aBuf  = ltab  + (size_t)32 * 512;              // 8192*32
    float* zlat = (float*)(aBuf + (size_t)8192 * 32);   // 256*128 f32

    // ---- weight conversion + leaf table (once per call) ----
    cvt_bf16<<<(1572864 + 255) / 256, 256, 0, stream>>>(ewh, ewh_b, 1572864);
    cvt_bf16<<<(1572864 + 255) / 256, 256, 0, stream>>>(dwh, dwh_b, 1572864);
    cvt_bf16<<<(98304 + 255) / 256, 256, 0, stream>>>(dwi, dwi_b, 98304);
    cvt_bf16<<<(16384 + 255) / 256, 256, 0, stream>>>(h2o_w, wo_b, 16384);
    leaf_tab<<<64, 256, 0, stream>>>(ewi, ebi, ebh, ltab);

    // ---- encoder ----
    enc_leaf<<<4096, 256, 0, stream>>>(ltab, symbols, bufL);
    const u16* src = bufL;
    u16*       dst = bufS;
    for (int d = 5; d >= 0; --d) {
        int M = 256 << d;
        enc_tile<<<dim3(M / 64, 8), 256, 0, stream>>>(src, ewh_b, ewi, ebi, ebh, symbols,
                                                      dst, d, (1 << d) - 1);
        const u16* t = src; src = dst; dst = (u16*)t;
    }
    // root in bufL
    mid1<<<256, 256, 0, stream>>>(src, h2mu_w, h2mu_b, h2lv_w, h2lv_b, eps, zlat, out_mu, out_lv);
    mid2<<<256, 512, 0, stream>>>(zlat, z2h_w, z2h_b, bufL);   // hidden0 -> bufL

    // ---- decoder ---- parity: d4 fills bufS exactly, d5 fills bufL exactly
    const u16* hsrc = bufL;
    u16*       hdst = bufS;
    for (int d = 0; d < 6; ++d) {
        int M = 256 << d;
        pred_mfma<<<M / 64, 256, 0, stream>>>(hsrc, wo_b, h2o_b, aBuf, out_pr, d, (1 << d) - 1, 1);
        dec_tile<<<dim3(M / 64, 16), 256, 0, stream>>>(hsrc, aBuf, dwh_b, dwi_b, dbh, dbi, hdst);
        const u16* t = hsrc; hsrc = hdst; hdst = (u16*)t;
    }
    pred_mfma<<<16384 / 64, 256, 0, stream>>>(hsrc, wo_b, h2o_b, aBuf, out_pr, 6, 63, 0);
}